// Round 8
// baseline (99.964 us; speedup 1.0000x reference)
//
#include <hip/hip_runtime.h>
#include <cstdint>

// Problem constants (from reference file)
constexpr int Bb = 8;     // batch
constexpr int Cc = 256;   // channels
constexpr int Tt = 1024;  // time
constexpr int Mm = 512;   // num_masked
constexpr int Kk = 100;   // negatives per position
constexpr int GRID = (Bb * Mm) / 2;   // 2048 blocks, 2 bm's each
#define EPSF 1e-8f
#define INV_TEMP 10.0f

typedef float vf4 __attribute__((ext_vector_type(4)));

// ---------------------------------------------------------------------------
// Fused main kernel. grid = 2048 blocks, 256 threads (4 waves).
// Block g handles bm0 = 2g and bm1 = 2g+1 (same mask row b = g>>8; their two
// 100x256 negative panels are CONTIGUOUS: 200 rows from nbase).
// R7 change: WAVE-CONTIGUOUS load pattern. Wave w, iteration it owns rows
// R..R+3 (R = it*16 + 4w); lane covers columns [lane*4, lane*4+4). Every
// global_load_dwordx4 is 1 KB contiguous (64 lanes x 16 B) — the same pattern
// as the 6.29 TB/s copy ubench — instead of 4 scattered 256B segments at
// 1KB stride. ctx fragment: ONE ds_read_b128 per iteration (identical for
// all 4 rows). Row dot/sq reduced by 64-lane butterfly (6 steps).
//   Entry:   prefetch iteration-0 rows (hides mask-scan/gather prologue).
//   Phase 0: mask element-width auto-detect (1/4/8B).
//   Phase 1: one prefix-scan of mask row -> t0 (m0-th set bit), t1 (m0+1-th).
//   Phase 2: gather ctx/pos columns t0,t1 -> LDS + norm/dot block-reduces.
//   Phase 3: unified 13-iteration stream over 200 rows (rows R..R+3 never
//            straddle the bm0/bm1 boundary since 100 % 4 == 0).
//   Phase 4: LSE(bm0) on wave 0 CONCURRENT with LSE(bm1) on wave 1.
// No cross-block communication (R3 lesson: per-block device fences = 5x).
// ---------------------------------------------------------------------------
__global__ __launch_bounds__(256)
void cl_main(const float* __restrict__ context,
             const float* __restrict__ positive,
             const float* __restrict__ negatives,
             const void*  __restrict__ mask,
             float*       __restrict__ lossbuf) {
    const int g    = blockIdx.x;           // 0..2047
    const int bm0  = g * 2;
    const int b    = bm0 >> 9;             // same row for bm0 and bm1
    const int m0   = bm0 & (Mm - 1);       // even; m0+1 <= 511 (same mask row)
    const int tid  = threadIdx.x;          // 0..255
    const int lane = tid & 63;
    const int wave = tid >> 6;             // 0..3

    __shared__ __align__(16) float ctx_s[2][Cc];   // contiguous: [1] = [0]+256
    __shared__ float redf[4][6];
    __shared__ int   redi[4][2];
    __shared__ int   scan_w[4];
    __shared__ float lraw[200];            // raw neg logits, r=0..199
    __shared__ int   t_sh[2];

    const long long nbase = (long long)bm0 * Kk * Cc;

    // ---- Entry: prefetch iteration-0 rows (R = 4*wave, rows 4w..4w+3) ----
    vf4 pre[4];
    {
        const float* rp0 = negatives + nbase + (long long)(wave * 4) * Cc + lane * 4;
        #pragma unroll
        for (int j = 0; j < 4; ++j)
            pre[j] = __builtin_nontemporal_load((const vf4*)(rp0 + j * Cc));
    }

    const uint8_t* p8  = (const uint8_t*)mask;
    const int32_t* p32 = (const int32_t*)mask;

    // ---- Phase 0: layout detection (first 1024 bytes / first 1024 ints) ----
    int c8 = 0, c32 = 0;
    #pragma unroll
    for (int j = 0; j < 4; ++j) {
        c8  += (p8 [j * 256 + tid] != 0);
        c32 += (p32[j * 256 + tid] != 0);
    }
    #pragma unroll
    for (int d = 32; d >= 1; d >>= 1) { c8 += __shfl_xor(c8, d); c32 += __shfl_xor(c32, d); }
    if (lane == 0) { redi[wave][0] = c8; redi[wave][1] = c32; }
    __syncthreads();
    const int tc8  = redi[0][0] + redi[1][0] + redi[2][0] + redi[3][0];
    const int tc32 = redi[0][1] + redi[1][1] + redi[2][1] + redi[3][1];
    const int esz  = (tc8 == Mm) ? 1 : ((tc32 == Mm) ? 4 : 8);

    // ---- Phase 1: prefix-scan mask row b; select m0-th and (m0+1)-th bits --
    int bits = 0;
    if (esz == 1) {
        const uint32_t w = *(const uint32_t*)(p8 + (size_t)b * Tt + tid * 4);
        bits = ((w & 0xffu)       ? 1 : 0) |
               ((w & 0xff00u)     ? 2 : 0) |
               ((w & 0xff0000u)   ? 4 : 0) |
               ((w & 0xff000000u) ? 8 : 0);
    } else if (esz == 4) {
        #pragma unroll
        for (int j = 0; j < 4; ++j)
            bits |= (p32[(size_t)b * Tt + tid * 4 + j] != 0) << j;
    } else {
        const int64_t* p64 = (const int64_t*)mask;
        #pragma unroll
        for (int j = 0; j < 4; ++j)
            bits |= (p64[(size_t)b * Tt + tid * 4 + j] != 0) << j;
    }
    const int cnt = __popc(bits);
    int incl = cnt;
    #pragma unroll
    for (int d = 1; d < 64; d <<= 1) { const int v = __shfl_up(incl, d); if (lane >= d) incl += v; }
    if (lane == 63) scan_w[wave] = incl;
    __syncthreads();
    int basec = 0;
    for (int w = 0; w < wave; ++w) basec += scan_w[w];
    incl += basec;
    const int excl = incl - cnt;
    #pragma unroll
    for (int sel = 0; sel < 2; ++sel) {
        const int mm = m0 + sel;
        if (excl <= mm && mm < incl) {
            int need = mm - excl;
            #pragma unroll
            for (int j = 0; j < 4; ++j) {
                if ((bits >> j) & 1) { if (need == 0) t_sh[sel] = tid * 4 + j; --need; }
            }
        }
    }
    __syncthreads();
    const int t0 = t_sh[0];
    const int t1 = t_sh[1];

    // ---- Phase 2: gather ctx/pos columns + block reduces ----
    const float* crow = context  + (size_t)(b * Cc + tid) * Tt;
    const float* prow = positive + (size_t)(b * Cc + tid) * Tt;
    const float cv0 = crow[t0];
    const float pv0 = prow[t0];
    const float cv1 = crow[t1];
    const float pv1 = prow[t1];
    ctx_s[0][tid] = cv0;
    ctx_s[1][tid] = cv1;

    float s0 = cv0 * cv0, s1 = pv0 * pv0, s2 = cv0 * pv0;
    float s3 = cv1 * cv1, s4 = pv1 * pv1, s5 = cv1 * pv1;
    #pragma unroll
    for (int d = 32; d >= 1; d >>= 1) {
        s0 += __shfl_xor(s0, d); s1 += __shfl_xor(s1, d); s2 += __shfl_xor(s2, d);
        s3 += __shfl_xor(s3, d); s4 += __shfl_xor(s4, d); s5 += __shfl_xor(s5, d);
    }
    if (lane == 0) {
        redf[wave][0] = s0; redf[wave][1] = s1; redf[wave][2] = s2;
        redf[wave][3] = s3; redf[wave][4] = s4; redf[wave][5] = s5;
    }
    __syncthreads();   // ctx_s + redf complete

    // ---- Phase 3: unified stream, wave-contiguous rows ----
    // process rows R..R+3 given their 4 loaded vf4's
    auto consume = [&](const vf4 nv[4], const vf4& c, int R) {
        float dotv[4], sqv[4];
        #pragma unroll
        for (int j = 0; j < 4; ++j) {
            dotv[j] = c.x * nv[j].x + c.y * nv[j].y + c.z * nv[j].z + c.w * nv[j].w;
            sqv[j]  = nv[j].x * nv[j].x + nv[j].y * nv[j].y + nv[j].z * nv[j].z + nv[j].w * nv[j].w;
        }
        #pragma unroll
        for (int j = 0; j < 4; ++j) {
            float dp = dotv[j], sq = sqv[j];
            #pragma unroll
            for (int d = 32; d >= 1; d >>= 1) { dp += __shfl_xor(dp, d); sq += __shfl_xor(sq, d); }
            if (lane == j) {
                const float nb = fmaxf(sqrtf(sq), EPSF);
                lraw[R + j] = dp / nb;     // raw: missing 10/||ctx||
            }
        }
    };

    // it = 0: consume prefetched rows (R = 4*wave < 100 -> ctx row 0)
    {
        const vf4 c = *(const vf4*)(ctx_s[0] + lane * 4);
        consume(pre, c, wave * 4);
    }

    // its 1..12
    #pragma unroll 2
    for (int it = 1; it < 13; ++it) {
        const int R = it * 16 + wave * 4;
        if (R < 200) {
            const vf4 c = *(const vf4*)(ctx_s[(R >= 100) ? 1 : 0] + lane * 4);
            const float* rp = negatives + nbase + (long long)R * Cc + lane * 4;
            vf4 nv[4];
            #pragma unroll
            for (int j = 0; j < 4; ++j)
                nv[j] = __builtin_nontemporal_load((const vf4*)(rp + j * Cc));
            consume(nv, c, R);
        }
    }
    __syncthreads();

    // ---- Phase 4: LSE(bm0) on wave 0, LSE(bm1) on wave 1, concurrently ----
    if (wave < 2) {
        const int o = wave * 3;
        const float na2 = redf[0][o]     + redf[1][o]     + redf[2][o]     + redf[3][o];
        const float np2 = redf[0][o + 1] + redf[1][o + 1] + redf[2][o + 1] + redf[3][o + 1];
        const float dcp = redf[0][o + 2] + redf[1][o + 2] + redf[2][o + 2] + redf[3][o + 2];
        const float na = fmaxf(sqrtf(na2), EPSF);
        const float np = fmaxf(sqrtf(np2), EPSF);
        const float scale = INV_TEMP / na;

        const float* lr = lraw + wave * Kk;   // 100 raw neg logits
        // values v0 = pos, v1..v100 = lr[0..99]; lane l holds v_l and v_{l+64}
        const float a_raw = (lane == 0) ? (dcp / np) : lr[lane - 1];
        const float b_raw = (lane + 64 <= Kk) ? lr[lane + 63] : -3e28f;
        const float a  = a_raw * scale;
        const float bb = b_raw * scale;
        float mx = fmaxf(a, bb);
        #pragma unroll
        for (int d = 32; d >= 1; d >>= 1) mx = fmaxf(mx, __shfl_xor(mx, d));
        float e = expf(a - mx) + expf(bb - mx);
        #pragma unroll
        for (int d = 32; d >= 1; d >>= 1) e += __shfl_xor(e, d);
        const float logit0 = __shfl(a, 0);
        if (lane == 0) lossbuf[bm0 + wave] = mx + logf(e) - logit0;
    }
}

// ---------------------------------------------------------------------------
// Deterministic mean over 4096 per-(b,m) losses.
// ---------------------------------------------------------------------------
__global__ __launch_bounds__(256)
void cl_reduce(const float* __restrict__ lossbuf, float* __restrict__ out) {
    const int tid = threadIdx.x;   // 0..255
    float s = 0.f;
    #pragma unroll
    for (int i = 0; i < 4; ++i) {
        const float4 v = *(const float4*)(lossbuf + tid * 16 + i * 4);
        s += (v.x + v.y) + (v.z + v.w);
    }
    #pragma unroll
    for (int d = 32; d >= 1; d >>= 1) s += __shfl_xor(s, d);
    __shared__ float ws[4];
    if ((tid & 63) == 0) ws[tid >> 6] = s;
    __syncthreads();
    if (tid == 0) out[0] = (ws[0] + ws[1] + ws[2] + ws[3]) * (1.0f / (Bb * Mm));
}

extern "C" void kernel_launch(void* const* d_in, const int* in_sizes, int n_in,
                              void* d_out, int out_size, void* d_ws, size_t ws_size,
                              hipStream_t stream) {
    const float* context   = (const float*)d_in[0];
    const float* positive  = (const float*)d_in[1];
    const float* negatives = (const float*)d_in[2];
    const void*  mask      = d_in[3];
    // d_in[4] = num_masked (512) — hardcoded as Mm.

    float* lossbuf = (float*)d_ws;    // 16 KB

    cl_main<<<GRID, 256, 0, stream>>>(context, positive, negatives, mask, lossbuf);
    cl_reduce<<<1, 256, 0, stream>>>(lossbuf, (float*)d_out);
}

// Round 9
// 76.446 us; speedup vs baseline: 1.3076x; 1.3076x over previous
//
#include <hip/hip_runtime.h>
#include <cstdint>

// Problem constants (from reference file)
constexpr int Bb = 8;     // batch
constexpr int Cc = 256;   // channels
constexpr int Tt = 1024;  // time
constexpr int Mm = 512;   // num_masked
constexpr int Kk = 100;   // negatives per position
constexpr int GRID = (Bb * Mm) / 2;   // 2048 blocks, 2 bm's each
#define EPSF 1e-8f
#define INV_TEMP 10.0f

typedef float vf4 __attribute__((ext_vector_type(4)));

// ---------------------------------------------------------------------------
// Fused main kernel. grid = 2048 blocks, 256 threads (4 waves).
// XCD swizzle (R8): g = (blockIdx&7)*256 + blockIdx>>3. Default dispatch puts
// blockIdx ≡ x (mod 8) on XCD x, so XCD x gets g in [256x, 256x+256) — all
// 256 blocks of ONE batch row b = g>>8. ctx[b]+pos[b] (2 MB) become
// L2-resident per XCD: the column-gather's L3->L2 line-fill traffic drops
// ~128 MB -> ~16 MB and stops contending with the negatives stream.
// Block g handles bm0 = 2g, bm1 = 2g+1 (same mask row; 200 contiguous rows).
// 16-lane-group structure (R6 — best measured; R8's wave-contiguous loads
// regressed: 6x shuffle cost outweighed pattern gain).
// No cross-block communication (R3 lesson: per-block device fences = 5x).
// ---------------------------------------------------------------------------
__global__ __launch_bounds__(256)
void cl_main(const float* __restrict__ context,
             const float* __restrict__ positive,
             const float* __restrict__ negatives,
             const void*  __restrict__ mask,
             float*       __restrict__ lossbuf) {
    const int g    = (blockIdx.x & 7) * (GRID / 8) + (blockIdx.x >> 3); // XCD swizzle
    const int bm0  = g * 2;
    const int b    = bm0 >> 9;             // same row for bm0 and bm1
    const int m0   = bm0 & (Mm - 1);       // even; m0+1 <= 511 (same mask row)
    const int tid  = threadIdx.x;          // 0..255
    const int lane = tid & 63;
    const int wave = tid >> 6;             // 0..3
    const int q    = lane & 15;
    const int ks   = lane >> 4;            // 0..3
    const int g16  = wave * 4 + ks;        // block-wide group id 0..15

    __shared__ __align__(16) float ctx_s[2][Cc];   // contiguous: [1] = [0]+256
    __shared__ float redf[4][6];
    __shared__ int   redi[4][2];
    __shared__ int   scan_w[4];
    __shared__ float lraw[200];            // raw neg logits, r=0..199
    __shared__ int   t_sh[2];

    const long long nbase = (long long)bm0 * Kk * Cc;

    // ---- Entry: prefetch iteration-0 rows (r = g16 < 16, always valid) ----
    vf4 pre[4];
    {
        const vf4* np4 = (const vf4*)(negatives + nbase + (long long)g16 * Cc);
        #pragma unroll
        for (int j = 0; j < 4; ++j) pre[j] = __builtin_nontemporal_load(np4 + j * 16 + q);
    }

    const uint8_t* p8  = (const uint8_t*)mask;
    const int32_t* p32 = (const int32_t*)mask;

    // ---- Phase 0: layout detection (first 1024 bytes / first 1024 ints) ----
    int c8 = 0, c32 = 0;
    #pragma unroll
    for (int j = 0; j < 4; ++j) {
        c8  += (p8 [j * 256 + tid] != 0);
        c32 += (p32[j * 256 + tid] != 0);
    }
    #pragma unroll
    for (int d = 32; d >= 1; d >>= 1) { c8 += __shfl_xor(c8, d); c32 += __shfl_xor(c32, d); }
    if (lane == 0) { redi[wave][0] = c8; redi[wave][1] = c32; }
    __syncthreads();
    const int tc8  = redi[0][0] + redi[1][0] + redi[2][0] + redi[3][0];
    const int tc32 = redi[0][1] + redi[1][1] + redi[2][1] + redi[3][1];
    const int esz  = (tc8 == Mm) ? 1 : ((tc32 == Mm) ? 4 : 8);

    // ---- Phase 1: prefix-scan mask row b; select m0-th and (m0+1)-th bits --
    int bits = 0;
    if (esz == 1) {
        const uint32_t w = *(const uint32_t*)(p8 + (size_t)b * Tt + tid * 4);
        bits = ((w & 0xffu)       ? 1 : 0) |
               ((w & 0xff00u)     ? 2 : 0) |
               ((w & 0xff0000u)   ? 4 : 0) |
               ((w & 0xff000000u) ? 8 : 0);
    } else if (esz == 4) {
        #pragma unroll
        for (int j = 0; j < 4; ++j)
            bits |= (p32[(size_t)b * Tt + tid * 4 + j] != 0) << j;
    } else {
        const int64_t* p64 = (const int64_t*)mask;
        #pragma unroll
        for (int j = 0; j < 4; ++j)
            bits |= (p64[(size_t)b * Tt + tid * 4 + j] != 0) << j;
    }
    const int cnt = __popc(bits);
    int incl = cnt;
    #pragma unroll
    for (int d = 1; d < 64; d <<= 1) { const int v = __shfl_up(incl, d); if (lane >= d) incl += v; }
    if (lane == 63) scan_w[wave] = incl;
    __syncthreads();
    int basec = 0;
    for (int w = 0; w < wave; ++w) basec += scan_w[w];
    incl += basec;
    const int excl = incl - cnt;
    #pragma unroll
    for (int sel = 0; sel < 2; ++sel) {
        const int mm = m0 + sel;
        if (excl <= mm && mm < incl) {
            int need = mm - excl;
            #pragma unroll
            for (int j = 0; j < 4; ++j) {
                if ((bits >> j) & 1) { if (need == 0) t_sh[sel] = tid * 4 + j; --need; }
            }
        }
    }
    __syncthreads();
    const int t0 = t_sh[0];
    const int t1 = t_sh[1];

    // ---- Phase 2: gather ctx/pos columns + block reduces ----
    const float* crow = context  + (size_t)(b * Cc + tid) * Tt;
    const float* prow = positive + (size_t)(b * Cc + tid) * Tt;
    const float cv0 = crow[t0];
    const float pv0 = prow[t0];
    const float cv1 = crow[t1];
    const float pv1 = prow[t1];
    ctx_s[0][tid] = cv0;
    ctx_s[1][tid] = cv1;

    float s0 = cv0 * cv0, s1 = pv0 * pv0, s2 = cv0 * pv0;
    float s3 = cv1 * cv1, s4 = pv1 * pv1, s5 = cv1 * pv1;
    #pragma unroll
    for (int d = 32; d >= 1; d >>= 1) {
        s0 += __shfl_xor(s0, d); s1 += __shfl_xor(s1, d); s2 += __shfl_xor(s2, d);
        s3 += __shfl_xor(s3, d); s4 += __shfl_xor(s4, d); s5 += __shfl_xor(s5, d);
    }
    if (lane == 0) {
        redf[wave][0] = s0; redf[wave][1] = s1; redf[wave][2] = s2;
        redf[wave][3] = s3; redf[wave][4] = s4; redf[wave][5] = s5;
    }
    __syncthreads();   // ctx_s + redf complete

    // ---- Phase 3: unified stream over 200 contiguous rows ----
    auto finish = [&](float dotp, float sq, int r) {
        #pragma unroll
        for (int d = 1; d <= 8; d <<= 1) {
            dotp += __shfl_xor(dotp, d);
            sq   += __shfl_xor(sq, d);
        }
        if (r < 200 && q == 0) {
            const float nb = fmaxf(sqrtf(sq), EPSF);
            lraw[r] = dotp / nb;           // raw: missing 10/||ctx||
        }
    };

    // it = 0: consume prefetched rows (ctx row 0, since r = g16 < 100)
    {
        const vf4* cp = (const vf4*)ctx_s[0];
        float dotp = 0.f, sq = 0.f;
        #pragma unroll
        for (int j = 0; j < 4; ++j) {
            const vf4 c  = cp[j * 16 + q];
            const vf4 nv = pre[j];
            dotp += c.x * nv.x + c.y * nv.y + c.z * nv.z + c.w * nv.w;
            sq   += nv.x * nv.x + nv.y * nv.y + nv.z * nv.z + nv.w * nv.w;
        }
        finish(dotp, sq, g16);
    }

    // its 1..12
    #pragma unroll 2
    for (int it = 1; it < 13; ++it) {
        const int r = it * 16 + g16;
        const vf4* cp = (const vf4*)(ctx_s[0] + ((r >= 100) ? Cc : 0));
        float dotp = 0.f, sq = 0.f;
        if (r < 200) {
            const vf4* np4 = (const vf4*)(negatives + nbase + (long long)r * Cc);
            #pragma unroll
            for (int j = 0; j < 4; ++j) {
                const vf4 nv = __builtin_nontemporal_load(np4 + j * 16 + q);
                const vf4 c  = cp[j * 16 + q];
                dotp += c.x * nv.x + c.y * nv.y + c.z * nv.z + c.w * nv.w;
                sq   += nv.x * nv.x + nv.y * nv.y + nv.z * nv.z + nv.w * nv.w;
            }
        }
        finish(dotp, sq, r);
    }
    __syncthreads();

    // ---- Phase 4: LSE(bm0) on wave 0, LSE(bm1) on wave 1, concurrently ----
    if (wave < 2) {
        const int o = wave * 3;
        const float na2 = redf[0][o]     + redf[1][o]     + redf[2][o]     + redf[3][o];
        const float np2 = redf[0][o + 1] + redf[1][o + 1] + redf[2][o + 1] + redf[3][o + 1];
        const float dcp = redf[0][o + 2] + redf[1][o + 2] + redf[2][o + 2] + redf[3][o + 2];
        const float na = fmaxf(sqrtf(na2), EPSF);
        const float np = fmaxf(sqrtf(np2), EPSF);
        const float scale = INV_TEMP / na;

        const float* lr = lraw + wave * Kk;   // 100 raw neg logits
        // values v0 = pos, v1..v100 = lr[0..99]; lane l holds v_l and v_{l+64}
        const float a_raw = (lane == 0) ? (dcp / np) : lr[lane - 1];
        const float b_raw = (lane + 64 <= Kk) ? lr[lane + 63] : -3e28f;
        const float a  = a_raw * scale;
        const float bb = b_raw * scale;
        float mx = fmaxf(a, bb);
        #pragma unroll
        for (int d = 32; d >= 1; d >>= 1) mx = fmaxf(mx, __shfl_xor(mx, d));
        float e = expf(a - mx) + expf(bb - mx);
        #pragma unroll
        for (int d = 32; d >= 1; d >>= 1) e += __shfl_xor(e, d);
        const float logit0 = __shfl(a, 0);
        if (lane == 0) lossbuf[bm0 + wave] = mx + logf(e) - logit0;
    }
}

// ---------------------------------------------------------------------------
// Deterministic mean over 4096 per-(b,m) losses.
// ---------------------------------------------------------------------------
__global__ __launch_bounds__(256)
void cl_reduce(const float* __restrict__ lossbuf, float* __restrict__ out) {
    const int tid = threadIdx.x;   // 0..255
    float s = 0.f;
    #pragma unroll
    for (int i = 0; i < 4; ++i) {
        const float4 v = *(const float4*)(lossbuf + tid * 16 + i * 4);
        s += (v.x + v.y) + (v.z + v.w);
    }
    #pragma unroll
    for (int d = 32; d >= 1; d >>= 1) s += __shfl_xor(s, d);
    __shared__ float ws[4];
    if ((tid & 63) == 0) ws[tid >> 6] = s;
    __syncthreads();
    if (tid == 0) out[0] = (ws[0] + ws[1] + ws[2] + ws[3]) * (1.0f / (Bb * Mm));
}

extern "C" void kernel_launch(void* const* d_in, const int* in_sizes, int n_in,
                              void* d_out, int out_size, void* d_ws, size_t ws_size,
                              hipStream_t stream) {
    const float* context   = (const float*)d_in[0];
    const float* positive  = (const float*)d_in[1];
    const float* negatives = (const float*)d_in[2];
    const void*  mask      = d_in[3];
    // d_in[4] = num_masked (512) — hardcoded as Mm.

    float* lossbuf = (float*)d_ws;    // 16 KB

    cl_main<<<GRID, 256, 0, stream>>>(context, positive, negatives, mask, lossbuf);
    cl_reduce<<<1, 256, 0, stream>>>(lossbuf, (float*)d_out);
}